// Round 3
// baseline (29.003 us; speedup 1.0000x reference)
//
#include <hip/hip_runtime.h>
#include <hip/hip_bf16.h>
#include <math.h>

// B=32768, L=24, H=64, V=64
#define B_SZ 32768
#define L_SZ 24
#define H_SZ 64
#define V_SZ 64

// Workspace (compact, float offsets)
#define KN_WS 0        // knTab[64][64]  (normalized h rows)
#define WK_WS 4096     // WkTab[64][64]  (h @ rp_w @ out_w rows)
#define NRM_WS 8192    // ||h|| per row [64]
#define B2_WS 8256     // bias2[64] = rp_b@out_w + out_b
#define CF_WS 8320     // coef[24] (23 used) = 1 - alpha_t
#define WS_F 8344      // = 2086 float4

// Scan-kernel LDS layout: chunk stride 12 floats (48 B) -> 8 lanes of a group
// start at banks {0,12,24,4,16,28,8,20}: perfect 32-bank tiling for ANY row.
#define ROW 96         // 8 chunks * 12 floats
#define KN_L 0
#define WK_L 6144
#define TL_L 12288     // tail: nrm[64], b2[64], cf[24]
#define LDS_F 12440    // 49.76 KB -> 3 blocks/CU

// ---------------------------------------------------------------------------
// Kernel A: fused table build. grid 65 x 64 threads (1 wave per block).
// Blocks 0..63: row v -> kn, nrm, Wk (all matvecs via shfl broadcast, fully
// coalesced global loads: for fixed k, lanes j read consecutive addresses).
// Block 64: bias2 + coef.
// ---------------------------------------------------------------------------
__global__ __launch_bounds__(64) void k_tab(
    const float* __restrict__ embed, const float* __restrict__ w1, const float* __restrict__ b1,
    const float* __restrict__ w2, const float* __restrict__ b2,
    const float* __restrict__ ln_g, const float* __restrict__ ln_b,
    const float* __restrict__ rp_w, const float* __restrict__ rp_b,
    const float* __restrict__ out_w, const float* __restrict__ out_b,
    const float* __restrict__ alpha_logits, float* __restrict__ ws)
{
  const int v = blockIdx.x;
  const int j = threadIdx.x;

  if (v < V_SZ) {
    const float ev = embed[v * H_SZ + j];
    // hidden = relu(e @ w1 + b1): lane j owns cols j and j+64
    float h0 = b1[j], h1 = b1[j + 64];
    #pragma unroll
    for (int k = 0; k < H_SZ; ++k) {
      const float ek = __shfl(ev, k);
      h0 = fmaf(ek, w1[k * 128 + j], h0);
      h1 = fmaf(ek, w1[k * 128 + 64 + j], h1);
    }
    h0 = fmaxf(h0, 0.0f);
    h1 = fmaxf(h1, 0.0f);
    // x = e + (hidden @ w2 + b2)
    float x = ev + b2[j];
    #pragma unroll
    for (int k = 0; k < H_SZ; ++k) {
      x = fmaf(__shfl(h0, k), w2[k * H_SZ + j], x);
      x = fmaf(__shfl(h1, k), w2[(k + 64) * H_SZ + j], x);
    }
    // LayerNorm
    float mu = x;
    #pragma unroll
    for (int m = 1; m < 64; m <<= 1) mu += __shfl_xor(mu, m);
    mu *= (1.0f / 64.0f);
    const float dv = x - mu;
    float var = dv * dv;
    #pragma unroll
    for (int m = 1; m < 64; m <<= 1) var += __shfl_xor(var, m);
    var *= (1.0f / 64.0f);
    const float y = dv * rsqrtf(var + 1e-5f) * ln_g[j] + ln_b[j];
    // norm + normalized row
    float n2 = y * y;
    #pragma unroll
    for (int m = 1; m < 64; m <<= 1) n2 += __shfl_xor(n2, m);
    const float nrm = sqrtf(n2);
    const float rn = 1.0f / fmaxf(nrm, 1e-12f);
    ws[KN_WS + v * H_SZ + j] = y * rn;
    if (j == 0) ws[NRM_WS + v] = nrm;
    // Wk row = (y @ rp_w) @ out_w
    float t1 = 0.0f;
    #pragma unroll
    for (int k = 0; k < H_SZ; ++k) t1 = fmaf(__shfl(y, k), rp_w[k * H_SZ + j], t1);
    float wk = 0.0f;
    #pragma unroll
    for (int k = 0; k < H_SZ; ++k) wk = fmaf(__shfl(t1, k), out_w[k * V_SZ + j], wk);
    ws[WK_WS + v * H_SZ + j] = wk;
  } else {
    float s = out_b[j];
    #pragma unroll
    for (int k = 0; k < H_SZ; ++k) s = fmaf(rp_b[k], out_w[k * V_SZ + j], s);
    ws[B2_WS + j] = s;
    if (j < L_SZ) {
      float cf = 0.0f;
      if (j < L_SZ - 1) {
        const float a = 1.0f / (1.0f + expf(-alpha_logits[j])) * 0.49f + 0.5f;
        cf = 1.0f - a;
      }
      ws[CF_WS + j] = cf;
    }
  }
}

// ---------------------------------------------------------------------------
// Kernel B: scan. 8 lanes per batch (8 floats each), 32 batches / 256-thr
// block, grid 1024 -> 3 blocks/CU (12 waves/CU). Backward recursion:
//   p = kn_tok . qhat   (3x shfl_xor reduce within 8-lane group)
//   c = (1-a_t) * p
//   oa += c * Wk[tok];  qhat -= c * kn_tok
// ---------------------------------------------------------------------------
__global__ __launch_bounds__(256) void k_scan(
    const int* __restrict__ seq, const float* __restrict__ ws, float* __restrict__ out)
{
  __shared__ float lds[LDS_F];
  const int tid = threadIdx.x;
  const float4* ws4 = (const float4*)ws;

  // Stage tables: compact [64][64] -> padded [64][ROW] chunk layout.
  for (int i = tid; i < 2048; i += 256) {
    const float4 f = ws4[i];
    float* base = (i & 1024) ? (lds + WK_L) : (lds + KN_L);
    const int r = (i >> 4) & 63;
    const int c = (i & 15) * 4;                 // 0,4,...,60
    *(float4*)(base + r * ROW + 12 * (c >> 3) + (c & 7)) = f;
  }
  for (int i = tid; i < 38; i += 256)
    *(((float4*)(lds + TL_L)) + i) = ws4[2048 + i];
  __syncthreads();

  const float* knL = lds + KN_L;
  const float* wkL = lds + WK_L;
  const float* nrmL = lds + TL_L;
  const float* b2L = lds + TL_L + 64;
  const float* cfL = lds + TL_L + 128;

  const int lane = tid & 63;
  const int wv = tid >> 6;
  const int g = lane >> 3;                       // batch within wave
  const int s = lane & 7;                        // 8-float chunk
  const int batch = blockIdx.x * 32 + wv * 8 + g;
  const int cb = 12 * s;                         // chunk base within row

  int sqv[L_SZ];
  const int4* sp = (const int4*)(seq + batch * L_SZ);
  #pragma unroll
  for (int i = 0; i < 6; ++i) ((int4*)sqv)[i] = sp[i];

  float qh[8], oa[8];
  {
    const int tok = sqv[L_SZ - 1];
    const float nv = nrmL[tok];
    const float* qr = knL + tok * ROW + cb;
    const float4 a = *(const float4*)qr;
    const float4 b = *(const float4*)(qr + 4);
    qh[0] = a.x * nv; qh[1] = a.y * nv; qh[2] = a.z * nv; qh[3] = a.w * nv;
    qh[4] = b.x * nv; qh[5] = b.y * nv; qh[6] = b.z * nv; qh[7] = b.w * nv;
  }
  #pragma unroll
  for (int i = 0; i < 8; ++i) oa[i] = 0.0f;

  #pragma unroll
  for (int t = L_SZ - 2; t >= 0; --t) {
    const int tok = sqv[t];
    const float* kr = knL + tok * ROW + cb;
    const float4 ka = *(const float4*)kr;
    const float4 kb = *(const float4*)(kr + 4);
    float kv[8] = {ka.x, ka.y, ka.z, ka.w, kb.x, kb.y, kb.z, kb.w};

    float p = 0.0f;
    #pragma unroll
    for (int i = 0; i < 8; ++i) p = fmaf(kv[i], qh[i], p);
    p += __shfl_xor(p, 1);
    p += __shfl_xor(p, 2);
    p += __shfl_xor(p, 4);                       // all 8 lanes: kn . qhat

    const float c = cfL[t] * p;

    #pragma unroll
    for (int i = 0; i < 8; ++i) qh[i] = fmaf(-c, kv[i], qh[i]);

    const float* wr = wkL + tok * ROW + cb;
    const float4 wa = *(const float4*)wr;
    const float4 wb = *(const float4*)(wr + 4);
    oa[0] = fmaf(c, wa.x, oa[0]); oa[1] = fmaf(c, wa.y, oa[1]);
    oa[2] = fmaf(c, wa.z, oa[2]); oa[3] = fmaf(c, wa.w, oa[3]);
    oa[4] = fmaf(c, wb.x, oa[4]); oa[5] = fmaf(c, wb.y, oa[5]);
    oa[6] = fmaf(c, wb.z, oa[6]); oa[7] = fmaf(c, wb.w, oa[7]);
  }

  #pragma unroll
  for (int i = 0; i < 8; ++i) oa[i] += b2L[s * 8 + i];

  float4* op = (float4*)(out + batch * V_SZ + s * 8);
  op[0] = make_float4(oa[0], oa[1], oa[2], oa[3]);
  op[1] = make_float4(oa[4], oa[5], oa[6], oa[7]);
}

// ---------------------------------------------------------------------------
extern "C" void kernel_launch(void* const* d_in, const int* in_sizes, int n_in,
                              void* d_out, int out_size, void* d_ws, size_t ws_size,
                              hipStream_t stream)
{
  const int*   seq          = (const int*)d_in[0];
  const float* embed        = (const float*)d_in[1];
  const float* w1           = (const float*)d_in[2];
  const float* b1           = (const float*)d_in[3];
  const float* w2           = (const float*)d_in[4];
  const float* b2           = (const float*)d_in[5];
  const float* ln_g         = (const float*)d_in[6];
  const float* ln_b         = (const float*)d_in[7];
  const float* rp_w         = (const float*)d_in[8];
  const float* rp_b         = (const float*)d_in[9];
  const float* out_w        = (const float*)d_in[10];
  const float* out_b        = (const float*)d_in[11];
  const float* alpha_logits = (const float*)d_in[12];
  float* ws   = (float*)d_ws;
  float* outp = (float*)d_out;

  hipLaunchKernelGGL(k_tab, dim3(V_SZ + 1), dim3(64), 0, stream,
                     embed, w1, b1, w2, b2, ln_g, ln_b,
                     rp_w, rp_b, out_w, out_b, alpha_logits, ws);
  hipLaunchKernelGGL(k_scan, dim3(B_SZ / 32), dim3(256), 0, stream,
                     seq, ws, outp);
}

// Round 4
// 27.842 us; speedup vs baseline: 1.0417x; 1.0417x over previous
//
#include <hip/hip_runtime.h>
#include <hip/hip_bf16.h>
#include <math.h>

// B=32768, L=24, H=64, V=64
#define B_SZ 32768
#define L_SZ 24
#define H_SZ 64
#define V_SZ 64

// Workspace (float offsets)
#define KN_WS 0        // kn[64][64]   normalized h rows
#define WK_WS 4096     // Wk[64][64]   h @ rp_w @ out_w rows
#define NRM_WS 8192    // ||h|| [64]
#define B2_WS 8256     // bias2[64]
#define CF_WS 8320     // cf[24] = 1 - alpha_t (cf[23]=0)
#define G_WS  8384     // Gram[64][64] = kn kn^T
#define WS_F  12480

// k_scan LDS layout (floats). Wk in chunk-12 layout: row stride 96,
// chunk s at 12*s -> 8 lanes of a group tile all 32 banks for ANY row.
#define ROW 96
#define G_L   0        // G[64][64] compact
#define WK_L  4096     // Wk[64][96]
#define NRM_L 10240    // nrm[64]
#define CB_L  10304    // c[64][24]
#define TO_L  11840    // wkOff int[64][24]
#define LDS_F 13376    // 53.5 KB -> 2-3 blocks/CU

// ---------------------------------------------------------------------------
// Kernel A: fused table build (identical to round-3 version, which validated).
// ---------------------------------------------------------------------------
__global__ __launch_bounds__(64) void k_tab(
    const float* __restrict__ embed, const float* __restrict__ w1, const float* __restrict__ b1,
    const float* __restrict__ w2, const float* __restrict__ b2,
    const float* __restrict__ ln_g, const float* __restrict__ ln_b,
    const float* __restrict__ rp_w, const float* __restrict__ rp_b,
    const float* __restrict__ out_w, const float* __restrict__ out_b,
    const float* __restrict__ alpha_logits, float* __restrict__ ws)
{
  const int v = blockIdx.x;
  const int j = threadIdx.x;

  if (v < V_SZ) {
    const float ev = embed[v * H_SZ + j];
    float h0 = b1[j], h1 = b1[j + 64];
    #pragma unroll
    for (int k = 0; k < H_SZ; ++k) {
      const float ek = __shfl(ev, k);
      h0 = fmaf(ek, w1[k * 128 + j], h0);
      h1 = fmaf(ek, w1[k * 128 + 64 + j], h1);
    }
    h0 = fmaxf(h0, 0.0f);
    h1 = fmaxf(h1, 0.0f);
    float x = ev + b2[j];
    #pragma unroll
    for (int k = 0; k < H_SZ; ++k) {
      x = fmaf(__shfl(h0, k), w2[k * H_SZ + j], x);
      x = fmaf(__shfl(h1, k), w2[(k + 64) * H_SZ + j], x);
    }
    float mu = x;
    #pragma unroll
    for (int m = 1; m < 64; m <<= 1) mu += __shfl_xor(mu, m);
    mu *= (1.0f / 64.0f);
    const float dv = x - mu;
    float var = dv * dv;
    #pragma unroll
    for (int m = 1; m < 64; m <<= 1) var += __shfl_xor(var, m);
    var *= (1.0f / 64.0f);
    const float y = dv * rsqrtf(var + 1e-5f) * ln_g[j] + ln_b[j];
    float n2 = y * y;
    #pragma unroll
    for (int m = 1; m < 64; m <<= 1) n2 += __shfl_xor(n2, m);
    const float nrm = sqrtf(n2);
    const float rn = 1.0f / fmaxf(nrm, 1e-12f);
    ws[KN_WS + v * H_SZ + j] = y * rn;
    if (j == 0) ws[NRM_WS + v] = nrm;
    float t1 = 0.0f;
    #pragma unroll
    for (int k = 0; k < H_SZ; ++k) t1 = fmaf(__shfl(y, k), rp_w[k * H_SZ + j], t1);
    float wk = 0.0f;
    #pragma unroll
    for (int k = 0; k < H_SZ; ++k) wk = fmaf(__shfl(t1, k), out_w[k * V_SZ + j], wk);
    ws[WK_WS + v * H_SZ + j] = wk;
  } else {
    float s = out_b[j];
    #pragma unroll
    for (int k = 0; k < H_SZ; ++k) s = fmaf(rp_b[k], out_w[k * V_SZ + j], s);
    ws[B2_WS + j] = s;
    if (j < L_SZ) {
      float cf = 0.0f;
      if (j < L_SZ - 1) {
        const float a = 1.0f / (1.0f + expf(-alpha_logits[j])) * 0.49f + 0.5f;
        cf = 1.0f - a;
      }
      ws[CF_WS + j] = cf;
    }
  }
}

// ---------------------------------------------------------------------------
// Kernel B: Gram table G[u][j] = kn[u] . kn[j]. grid 64 x 64.
// ---------------------------------------------------------------------------
__global__ __launch_bounds__(64) void k_gram(float* __restrict__ ws)
{
  const int u = blockIdx.x;
  const int j = threadIdx.x;
  const float a = ws[KN_WS + u * H_SZ + j];     // lane j holds kn[u][j]
  float r[64];
  const float4* rp = (const float4*)(ws + KN_WS + j * H_SZ);
  #pragma unroll
  for (int i = 0; i < 16; ++i) {
    const float4 f = rp[i];
    r[4 * i] = f.x; r[4 * i + 1] = f.y; r[4 * i + 2] = f.z; r[4 * i + 3] = f.w;
  }
  float s = 0.0f;
  #pragma unroll
  for (int k = 0; k < 64; ++k) s = fmaf(__shfl(a, k), r[k], s);
  ws[G_WS + u * H_SZ + j] = s;
}

// ---------------------------------------------------------------------------
// Kernel C: scan. 64 batches/block, grid 512, 256 threads.
// Phase A (16 lanes/wave, 1 lane = 1 batch): scalar Gram recursion ->
//   c_t = cf_t*(nrm_q*G[g_t][g_q] - sum_{s>t} c_s*G[g_t][g_s])
//   (running partials P[t], fully unrolled triangle, ~2-FMA serial chain/step)
// Phase B (8 lanes/batch): out[b] = b2 + sum_t c_t * Wk[g_t], conflict-free
//   chunk-12 Wk reads.
// ---------------------------------------------------------------------------
__global__ __launch_bounds__(256) void k_scan(
    const int* __restrict__ seq, const float* __restrict__ ws, float* __restrict__ out)
{
  __shared__ float lds[LDS_F];
  const int tid = threadIdx.x;
  const float4* ws4 = (const float4*)ws;

  // Stage G (linear) and Wk (chunk-12 relayout), nrm.
  for (int i = tid; i < 1024; i += 256)
    ((float4*)(lds + G_L))[i] = ws4[G_WS / 4 + i];
  for (int i = tid; i < 1024; i += 256) {
    const float4 f = ws4[WK_WS / 4 + i];
    const int r = i >> 4;
    const int c = (i & 15) * 4;
    *(float4*)(lds + WK_L + r * ROW + 12 * (c >> 3) + (c & 7)) = f;
  }
  if (tid < 16) ((float4*)(lds + NRM_L))[tid] = ws4[NRM_WS / 4 + tid];
  __syncthreads();

  const int lane = tid & 63;
  const int wv = tid >> 6;
  const float* cfg = ws + CF_WS;   // uniform -> scalar loads

  // ---- Phase A ----
  if (lane < 16) {
    const int ab = wv * 16 + lane;
    const int batch = blockIdx.x * 64 + ab;
    int g[24];
    const int4* sp = (const int4*)(seq + batch * L_SZ);
    #pragma unroll
    for (int i = 0; i < 6; ++i) {
      const int4 t4 = sp[i];
      g[4 * i] = t4.x; g[4 * i + 1] = t4.y; g[4 * i + 2] = t4.z; g[4 * i + 3] = t4.w;
    }
    int* tob = (int*)lds + TO_L + ab * 24;
    #pragma unroll
    for (int i = 0; i < 6; ++i)
      ((int4*)tob)[i] = make_int4(g[4 * i] * ROW, g[4 * i + 1] * ROW,
                                  g[4 * i + 2] * ROW, g[4 * i + 3] * ROW);
    const int q = g[23];
    const float nl = lds[NRM_L + q];
    const float* Gt = lds + G_L;
    float* cb = lds + CB_L + ab * 24;
    float P[23];
    #pragma unroll
    for (int t = 0; t < 23; ++t) P[t] = 0.0f;
    #pragma unroll
    for (int s = 22; s >= 0; --s) {
      const float base = nl * Gt[(g[s] << 6) + q];
      const float cs = cfg[s] * (base - P[s]);
      cb[s] = cs;
      #pragma unroll
      for (int t = 0; t < s; ++t)
        P[t] = fmaf(cs, Gt[(g[t] << 6) + g[s]], P[t]);
    }
    cb[23] = 0.0f;
  }
  __syncthreads();

  // ---- Phase B ----
  const int grp = lane >> 3;
  const int s8 = lane & 7;
  const int cbse = 12 * s8;
  const float* wkL = lds + WK_L;
  const float* b2g = ws + B2_WS + s8 * 8;
  const float4 bA = *(const float4*)(b2g);
  const float4 bB = *(const float4*)(b2g + 4);

  #pragma unroll
  for (int it = 0; it < 2; ++it) {
    const int ab = wv * 16 + it * 8 + grp;
    const int batch = blockIdx.x * 64 + ab;
    float cv[24]; int tv[24];
    const float4* cp = (const float4*)(lds + CB_L + ab * 24);
    const int4* tp = (const int4*)((const int*)lds + TO_L + ab * 24);
    #pragma unroll
    for (int i = 0; i < 6; ++i) {
      const float4 f = cp[i];
      cv[4 * i] = f.x; cv[4 * i + 1] = f.y; cv[4 * i + 2] = f.z; cv[4 * i + 3] = f.w;
      const int4 t4 = tp[i];
      tv[4 * i] = t4.x; tv[4 * i + 1] = t4.y; tv[4 * i + 2] = t4.z; tv[4 * i + 3] = t4.w;
    }
    float oa[8] = {bA.x, bA.y, bA.z, bA.w, bB.x, bB.y, bB.z, bB.w};
    #pragma unroll
    for (int t = 0; t < 23; ++t) {
      const float c = cv[t];
      const float* wr = wkL + tv[t] + cbse;
      const float4 wa = *(const float4*)wr;
      const float4 wb = *(const float4*)(wr + 4);
      oa[0] = fmaf(c, wa.x, oa[0]); oa[1] = fmaf(c, wa.y, oa[1]);
      oa[2] = fmaf(c, wa.z, oa[2]); oa[3] = fmaf(c, wa.w, oa[3]);
      oa[4] = fmaf(c, wb.x, oa[4]); oa[5] = fmaf(c, wb.y, oa[5]);
      oa[6] = fmaf(c, wb.z, oa[6]); oa[7] = fmaf(c, wb.w, oa[7]);
    }
    float4* op = (float4*)(out + batch * V_SZ + s8 * 8);
    op[0] = make_float4(oa[0], oa[1], oa[2], oa[3]);
    op[1] = make_float4(oa[4], oa[5], oa[6], oa[7]);
  }
}

// ---------------------------------------------------------------------------
extern "C" void kernel_launch(void* const* d_in, const int* in_sizes, int n_in,
                              void* d_out, int out_size, void* d_ws, size_t ws_size,
                              hipStream_t stream)
{
  const int*   seq          = (const int*)d_in[0];
  const float* embed        = (const float*)d_in[1];
  const float* w1           = (const float*)d_in[2];
  const float* b1           = (const float*)d_in[3];
  const float* w2           = (const float*)d_in[4];
  const float* b2           = (const float*)d_in[5];
  const float* ln_g         = (const float*)d_in[6];
  const float* ln_b         = (const float*)d_in[7];
  const float* rp_w         = (const float*)d_in[8];
  const float* rp_b         = (const float*)d_in[9];
  const float* out_w        = (const float*)d_in[10];
  const float* out_b        = (const float*)d_in[11];
  const float* alpha_logits = (const float*)d_in[12];
  float* ws   = (float*)d_ws;
  float* outp = (float*)d_out;

  hipLaunchKernelGGL(k_tab, dim3(V_SZ + 1), dim3(64), 0, stream,
                     embed, w1, b1, w2, b2, ln_g, ln_b,
                     rp_w, rp_b, out_w, out_b, alpha_logits, ws);
  hipLaunchKernelGGL(k_gram, dim3(V_SZ), dim3(64), 0, stream, ws);
  hipLaunchKernelGGL(k_scan, dim3(B_SZ / 64), dim3(256), 0, stream,
                     seq, ws, outp);
}